// Round 16
// baseline (121.508 us; speedup 1.0000x reference)
//
#include <hip/hip_runtime.h>
#include <math.h>

#define NHID 512
#define T_K  256
#define T_Q  128
#define BB   8

// tanh(x) = 1 - 2/(exp2(C*x)+1), C = 2*log2(e)
constexpr float C2L2E = 2.8853900817779268f;
constexpr float L2E   = 1.4426950408889634f;

__device__ __forceinline__ float fexp2(float x) { return __builtin_amdgcn_exp2f(x); }
__device__ __forceinline__ float frcp(float x)  { return __builtin_amdgcn_rcpf(x); }

typedef __attribute__((ext_vector_type(8))) short bf16x8;
typedef __attribute__((ext_vector_type(4))) float f32x4;

__device__ __forceinline__ unsigned short f2bf(float x) {
    unsigned u = __builtin_bit_cast(unsigned, x);
    unsigned r = (u + 0x7FFFu + ((u >> 16) & 1u)) >> 16;
    return (unsigned short)r;
}
__device__ __forceinline__ float bf2f(unsigned short h) {
    unsigned u = ((unsigned)h) << 16;
    return __builtin_bit_cast(float, u);
}
__device__ __forceinline__ unsigned packbf(float a, float b) {
    return (unsigned)f2bf(a) | ((unsigned)f2bf(b) << 16);
}
__device__ __forceinline__ float lo16(unsigned u) {
    return __builtin_bit_cast(float, u << 16);
}
__device__ __forceinline__ float hi16(unsigned u) {
    return __builtin_bit_cast(float, u & 0xFFFF0000u);
}

// ---------------------------------------------------------------------------
// Kernel 1: proj GEMM with in-kernel W1 transpose/split + free ckp emission.
// (R15 structure, unchanged)
// ---------------------------------------------------------------------------
__global__ __launch_bounds__(256) void proj_kernel(
    const float* __restrict__ qry, const float* __restrict__ ckey,
    const float* __restrict__ W1, const float* __restrict__ b1,
    uint2* __restrict__ ektq, float* __restrict__ eq,
    unsigned int* __restrict__ ckp)
{
    const int row0 = blockIdx.x * 32;
    const int col0 = blockIdx.y * 64;
    const bool isK = row0 < 2048;
    const int bhalf = isK ? 0 : 512;

    __shared__ __align__(16) unsigned short As_h[32 * 64];
    __shared__ __align__(16) unsigned short As_l[32 * 64];
    __shared__ __align__(16) unsigned short Bs_h[64 * 64];
    __shared__ __align__(16) unsigned short Bs_l[64 * 64];

    const int t    = threadIdx.x;
    const int wave = t >> 6;
    const int lane = t & 63;
    const int wm = (wave & 1) * 16;
    const int wn = (wave >> 1) * 32;

    f32x4 acc[2] = {};

    const int srA = t >> 3;
    const int scA = (t & 7) * 8;
    const float* gA = (isK ? ckey + (size_t)(row0 + srA) * 512
                           : qry  + (size_t)(row0 - 2048 + srA) * 512) + scA;
    const int swA = ((scA >> 3) ^ (srA & 7)) * 8;
    const bool emit_ckp = isK && (col0 == 0);
    const int rowA = row0 + srA;
    unsigned int* ckp_dst = emit_ckp
        ? ckp + ((size_t)(rowA & 7) * 256 + (rowA >> 3)) * 256
        : nullptr;

    const int nB = t & 63;
    const int kgB = wave * 16;
    const float* gB = W1 + (size_t)(bhalf + kgB) * 512 + col0 + nB;
    const int caB = wave * 2;
    const int swB0 = nB * 64 + (((caB + 0) ^ (nB & 7)) * 8);
    const int swB1 = nB * 64 + (((caB + 1) ^ (nB & 7)) * 8);

    const int quad = lane >> 4, fr = lane & 15;

    float4 pa0 = *(const float4*)&gA[0];
    float4 pa1 = *(const float4*)&gA[4];
    float bv[16];
    #pragma unroll
    for (int kk = 0; kk < 16; ++kk)
        bv[kk] = gB[(size_t)kk * 512];

    for (int k0 = 0; k0 < 512; k0 += 64) {
        float fa[8];
        *(float4*)&fa[0] = pa0; *(float4*)&fa[4] = pa1;
        union { uint4 v; unsigned short s[8]; } hA, lA, bh0, bh1, bl0, bl1;
        #pragma unroll
        for (int e = 0; e < 8; ++e) {
            const unsigned short hb = f2bf(fa[e]);
            hA.s[e] = hb; lA.s[e] = f2bf(fa[e] - bf2f(hb));
        }
        #pragma unroll
        for (int e = 0; e < 8; ++e) {
            const unsigned short hb = f2bf(bv[e]);
            bh0.s[e] = hb; bl0.s[e] = f2bf(bv[e] - bf2f(hb));
        }
        #pragma unroll
        for (int e = 0; e < 8; ++e) {
            const unsigned short hb = f2bf(bv[8 + e]);
            bh1.s[e] = hb; bl1.s[e] = f2bf(bv[8 + e] - bf2f(hb));
        }
        if (emit_ckp)
            *(uint4*)&ckp_dst[(k0 + scA) >> 1] = hA.v;

        __syncthreads();
        *(uint4*)&As_h[srA * 64 + swA] = hA.v;
        *(uint4*)&As_l[srA * 64 + swA] = lA.v;
        *(uint4*)&Bs_h[swB0] = bh0.v;  *(uint4*)&Bs_h[swB1] = bh1.v;
        *(uint4*)&Bs_l[swB0] = bl0.v;  *(uint4*)&Bs_l[swB1] = bl1.v;
        __syncthreads();

        if (k0 + 64 < 512) {
            pa0 = *(const float4*)&gA[k0 + 64];
            pa1 = *(const float4*)&gA[k0 + 68];
            #pragma unroll
            for (int kk = 0; kk < 16; ++kk)
                bv[kk] = gB[(size_t)(k0 + 64 + kk) * 512];
        }

        #pragma unroll
        for (int ks = 0; ks < 2; ++ks) {
            const int cchunk = ks * 4 + quad;
            const int m = wm + fr;
            const bf16x8 afh = *(const bf16x8*)&As_h[m * 64 + ((cchunk ^ (m & 7)) * 8)];
            const bf16x8 afl = *(const bf16x8*)&As_l[m * 64 + ((cchunk ^ (m & 7)) * 8)];
            bf16x8 bfh[2], bfl[2];
            #pragma unroll
            for (int nt = 0; nt < 2; ++nt) {
                const int n = wn + nt * 16 + fr;
                bfh[nt] = *(const bf16x8*)&Bs_h[n * 64 + ((cchunk ^ (n & 7)) * 8)];
                bfl[nt] = *(const bf16x8*)&Bs_l[n * 64 + ((cchunk ^ (n & 7)) * 8)];
            }
            #pragma unroll
            for (int nt = 0; nt < 2; ++nt) {
                acc[nt] = __builtin_amdgcn_mfma_f32_16x16x32_bf16(afh, bfh[nt], acc[nt], 0, 0, 0);
                acc[nt] = __builtin_amdgcn_mfma_f32_16x16x32_bf16(afh, bfl[nt], acc[nt], 0, 0, 0);
                acc[nt] = __builtin_amdgcn_mfma_f32_16x16x32_bf16(afl, bfh[nt], acc[nt], 0, 0, 0);
            }
        }
    }

    #pragma unroll
    for (int nt = 0; nt < 2; ++nt) {
        const int colg = col0 + wn + nt * 16 + fr;
        const float b1v = b1[colg];
        #pragma unroll
        for (int i = 0; i < 4; ++i) {
            const int rowg = row0 + wm + quad * 4 + i;
            const float v = acc[nt][i];
            if (isK) {
                const float e = fexp2((v + b1v) * C2L2E);
                const float ep = __shfl_xor(e, 1, 64);
                unsigned pk = ((fr & 1) == 0) ? packbf(e, ep) : packbf(ep, e);
                const unsigned pk2 = __shfl_xor(pk, 2, 64);
                if ((fr & 3) == 0) {
                    const int kidx = rowg >> 3;
                    const int bb   = rowg & 7;
                    const int hq   = colg >> 2;
                    ektq[((size_t)bb * 128 + hq) * 256 + kidx] = make_uint2(pk, pk2);
                }
            } else {
                eq[(size_t)(rowg - 2048) * 512 + colg] = fexp2(v * C2L2E);
            }
        }
    }
}

// ---------------------------------------------------------------------------
// Kernel 2: fused score + softmax + antvec — ONE q per block.
// Grid (128,8) = 1024 blocks; __launch_bounds__(512,8) targets 4 blocks/CU
// = 8 waves/SIMD (R15: the 512-block grid capped occupancy at 2/CU and the
// score phase sat at ~50% stall). Same math, half the per-block state.
// ---------------------------------------------------------------------------
__global__ __launch_bounds__(512, 8) void scoreav_kernel(
    const uint2* __restrict__ ektq, const float* __restrict__ eq,
    const float* __restrict__ W2, const float* __restrict__ b2,
    const int* __restrict__ mask, const unsigned int* __restrict__ ckp,
    float* __restrict__ prob_out, float* __restrict__ out_ant)
{
    const int t    = threadIdx.x;
    const int lane = t & 63;
    const int wave = __builtin_amdgcn_readfirstlane(t >> 6);
    const int kk   = t & 255;
    const int half = t >> 8;
    const int q    = blockIdx.x;
    const int b    = blockIdx.y;

    __shared__ float eqs[512], w2s[512];   // 4 KB
    __shared__ float rp[512];              // 2 KB
    __shared__ float ps[256];              // 1 KB

    eqs[t] = eq[((size_t)q * 8 + b) * 512 + t];
    w2s[t] = W2[t];

    const float4 wA = *(const float4*)&W2[lane * 4];
    const float4 wB = *(const float4*)&W2[256 + lane * 4];
    float s2 = wA.x + wA.y + wA.z + wA.w + wB.x + wB.y + wB.z + wB.w;
    #pragma unroll
    for (int m = 32; m; m >>= 1) s2 += __shfl_xor(s2, m, 64);
    const float base = s2 + b2[0];
    __syncthreads();

    // ---- score: double-buffered 8-load batches, 2 acc chains ----
    const uint2* __restrict__ ekb = ektq + (size_t)b * 128 * 256 + kk;
    float ra = 0.f, rb = 0.f;

    uint2 L[2][8];
    #pragma unroll
    for (int j = 0; j < 8; ++j)
        L[0][j] = ekb[(size_t)(half * 64 + j) * 256];

    for (int g = 0; g < 8; ++g) {
        const int cur = g & 1;
        if (g < 7) {
            #pragma unroll
            for (int j = 0; j < 8; ++j)
                L[cur ^ 1][j] = ekb[(size_t)(half * 64 + (g + 1) * 8 + j) * 256];
        }
        #pragma unroll
        for (int j = 0; j < 8; ++j) {
            const int h = (half * 64 + g * 8 + j) * 4;
            const float ek0 = lo16(L[cur][j].x);
            const float ek1 = hi16(L[cur][j].x);
            const float ek2 = lo16(L[cur][j].y);
            const float ek3 = hi16(L[cur][j].y);
            const float4 w  = *(const float4*)&w2s[h];
            const float4 e0 = *(const float4*)&eqs[h];
            const float a0 = fmaf(ek0, e0.x, 1.0f);
            const float a1 = fmaf(ek1, e0.y, 1.0f);
            const float a2 = fmaf(ek2, e0.z, 1.0f);
            const float a3 = fmaf(ek3, e0.w, 1.0f);
            const float d01 = a0 * a1, d23 = a2 * a3;
            const float n01 = fmaf(w.x, a1, w.y * a0);
            const float n23 = fmaf(w.z, a3, w.w * a2);
            const float N = fmaf(n01, d23, n23 * d01);
            if (j & 1) rb = fmaf(N, frcp(d01 * d23), rb);
            else       ra = fmaf(N, frcp(d01 * d23), ra);
        }
    }
    rp[t] = ra + rb;
    __syncthreads();

    if (t < 256) {
        const int msk = mask[t * 8 + b];
        float s0 = base - 2.0f * (rp[t] + rp[t + 256]);
        if (msk) s0 = -INFINITY;
        ps[t] = s0;
    }
    __syncthreads();

    // ---- softmax: wave 0 ----
    if (wave == 0) {
        float4 sv = *(const float4*)&ps[lane * 4];
        float m = fmaxf(fmaxf(sv.x, sv.y), fmaxf(sv.z, sv.w));
        #pragma unroll
        for (int d = 32; d; d >>= 1) m = fmaxf(m, __shfl_xor(m, d, 64));
        float4 pv;
        pv.x = fexp2((sv.x - m) * L2E);
        pv.y = fexp2((sv.y - m) * L2E);
        pv.z = fexp2((sv.z - m) * L2E);
        pv.w = fexp2((sv.w - m) * L2E);
        float sum = pv.x + pv.y + pv.z + pv.w;
        #pragma unroll
        for (int d = 32; d; d >>= 1) sum += __shfl_xor(sum, d, 64);
        const float inv = frcp(sum);
        pv.x *= inv; pv.y *= inv; pv.z *= inv; pv.w *= inv;
        *(float4*)&ps[lane * 4] = pv;
        const int qb_idx = q * 8 + b;
        const int kbase = lane * 4;
        prob_out[(size_t)(kbase + 0) * 1024 + qb_idx] = pv.x;
        prob_out[(size_t)(kbase + 1) * 1024 + qb_idx] = pv.y;
        prob_out[(size_t)(kbase + 2) * 1024 + qb_idx] = pv.z;
        prob_out[(size_t)(kbase + 3) * 1024 + qb_idx] = pv.w;
    }
    __syncthreads();

    // ---- antvec: 8 waves, wave -> 64 h, lane -> (k-residue, h-quad) ----
    {
        const int kq  = lane >> 4;         // 0..3
        const int hq2 = lane & 15;         // 0..15
        const int pbase = wave * 32 + hq2 * 2;
        const unsigned int* __restrict__ ckb = ckp + (size_t)b * 256 * 256;
        float4 a0 = {};
        #pragma unroll 8
        for (int ki = 0; ki < 64; ++ki) {
            const int k = ki * 4 + kq;
            const uint2 U = *(const uint2*)&ckb[(size_t)k * 256 + pbase];
            const float p0 = ps[k];
            a0.x = fmaf(p0, lo16(U.x), a0.x);
            a0.y = fmaf(p0, hi16(U.x), a0.y);
            a0.z = fmaf(p0, lo16(U.y), a0.z);
            a0.w = fmaf(p0, hi16(U.y), a0.w);
        }
        #pragma unroll
        for (int d = 16; d <= 32; d <<= 1) {
            a0.x += __shfl_xor(a0.x, d, 64); a0.y += __shfl_xor(a0.y, d, 64);
            a0.z += __shfl_xor(a0.z, d, 64); a0.w += __shfl_xor(a0.w, d, 64);
        }
        if (lane < 16) {
            const int h0 = wave * 64 + hq2 * 4;
            *(float4*)&out_ant[((size_t)q * 8 + b) * 512 + h0] = a0;
        }
    }
}

// ---------------------------------------------------------------------------
extern "C" void kernel_launch(void* const* d_in, const int* in_sizes, int n_in,
                              void* d_out, int out_size, void* d_ws, size_t ws_size,
                              hipStream_t stream)
{
    const float* qry  = (const float*)d_in[0];
    const float* ckey = (const float*)d_in[1];
    const int*   mask = (const int*)d_in[2];
    const float* W1   = (const float*)d_in[3];
    const float* b1   = (const float*)d_in[4];
    const float* W2   = (const float*)d_in[5];
    const float* b2   = (const float*)d_in[6];

    float* out_ant  = (float*)d_out;
    float* out_prob = (float*)d_out + T_Q * BB * NHID;

    float* ws = (float*)d_ws;
    uint2* ws_ektq = (uint2*)ws;                              // [8][128][256] uint2, 2MB
    float* ws_eq  = ws + 524288;                              // [1024][512] f32, 2MB
    unsigned int* ws_ckp = (unsigned int*)(ws + 1048576);     // [8][256][256] u32, 2MB

    proj_kernel<<<dim3(96, 8), 256, 0, stream>>>(qry, ckey, W1, b1,
                                                 ws_ektq, ws_eq, ws_ckp);
    scoreav_kernel<<<dim3(128, 8), 512, 0, stream>>>(ws_ektq, ws_eq, W2, b2, mask, ws_ckp,
                                                     out_prob, out_ant);
}

// Round 17
// 112.421 us; speedup vs baseline: 1.0808x; 1.0808x over previous
//
#include <hip/hip_runtime.h>
#include <math.h>

#define NHID 512
#define T_K  256
#define T_Q  128
#define BB   8

// tanh(x) = 1 - 2/(exp2(C*x)+1), C = 2*log2(e)
constexpr float C2L2E = 2.8853900817779268f;
constexpr float L2E   = 1.4426950408889634f;

__device__ __forceinline__ float fexp2(float x) { return __builtin_amdgcn_exp2f(x); }
__device__ __forceinline__ float frcp(float x)  { return __builtin_amdgcn_rcpf(x); }

typedef __attribute__((ext_vector_type(8))) short bf16x8;
typedef __attribute__((ext_vector_type(4))) float f32x4;

__device__ __forceinline__ unsigned short f2bf(float x) {
    unsigned u = __builtin_bit_cast(unsigned, x);
    unsigned r = (u + 0x7FFFu + ((u >> 16) & 1u)) >> 16;
    return (unsigned short)r;
}
__device__ __forceinline__ float bf2f(unsigned short h) {
    unsigned u = ((unsigned)h) << 16;
    return __builtin_bit_cast(float, u);
}
__device__ __forceinline__ unsigned packbf(float a, float b) {
    return (unsigned)f2bf(a) | ((unsigned)f2bf(b) << 16);
}
__device__ __forceinline__ float lo16(unsigned u) {
    return __builtin_bit_cast(float, u << 16);
}
__device__ __forceinline__ float hi16(unsigned u) {
    return __builtin_bit_cast(float, u & 0xFFFF0000u);
}

// ---------------------------------------------------------------------------
// Kernel 1: proj GEMM with in-kernel W1 transpose/split + free ckp emission.
// (R15 structure, unchanged)
// ---------------------------------------------------------------------------
__global__ __launch_bounds__(256) void proj_kernel(
    const float* __restrict__ qry, const float* __restrict__ ckey,
    const float* __restrict__ W1, const float* __restrict__ b1,
    uint2* __restrict__ ektq, float* __restrict__ eq,
    unsigned int* __restrict__ ckp)
{
    const int row0 = blockIdx.x * 32;
    const int col0 = blockIdx.y * 64;
    const bool isK = row0 < 2048;
    const int bhalf = isK ? 0 : 512;

    __shared__ __align__(16) unsigned short As_h[32 * 64];
    __shared__ __align__(16) unsigned short As_l[32 * 64];
    __shared__ __align__(16) unsigned short Bs_h[64 * 64];
    __shared__ __align__(16) unsigned short Bs_l[64 * 64];

    const int t    = threadIdx.x;
    const int wave = t >> 6;
    const int lane = t & 63;
    const int wm = (wave & 1) * 16;
    const int wn = (wave >> 1) * 32;

    f32x4 acc[2] = {};

    const int srA = t >> 3;
    const int scA = (t & 7) * 8;
    const float* gA = (isK ? ckey + (size_t)(row0 + srA) * 512
                           : qry  + (size_t)(row0 - 2048 + srA) * 512) + scA;
    const int swA = ((scA >> 3) ^ (srA & 7)) * 8;
    const bool emit_ckp = isK && (col0 == 0);
    const int rowA = row0 + srA;
    unsigned int* ckp_dst = emit_ckp
        ? ckp + ((size_t)(rowA & 7) * 256 + (rowA >> 3)) * 256
        : nullptr;

    const int nB = t & 63;
    const int kgB = wave * 16;
    const float* gB = W1 + (size_t)(bhalf + kgB) * 512 + col0 + nB;
    const int caB = wave * 2;
    const int swB0 = nB * 64 + (((caB + 0) ^ (nB & 7)) * 8);
    const int swB1 = nB * 64 + (((caB + 1) ^ (nB & 7)) * 8);

    const int quad = lane >> 4, fr = lane & 15;

    float4 pa0 = *(const float4*)&gA[0];
    float4 pa1 = *(const float4*)&gA[4];
    float bv[16];
    #pragma unroll
    for (int kk = 0; kk < 16; ++kk)
        bv[kk] = gB[(size_t)kk * 512];

    for (int k0 = 0; k0 < 512; k0 += 64) {
        float fa[8];
        *(float4*)&fa[0] = pa0; *(float4*)&fa[4] = pa1;
        union { uint4 v; unsigned short s[8]; } hA, lA, bh0, bh1, bl0, bl1;
        #pragma unroll
        for (int e = 0; e < 8; ++e) {
            const unsigned short hb = f2bf(fa[e]);
            hA.s[e] = hb; lA.s[e] = f2bf(fa[e] - bf2f(hb));
        }
        #pragma unroll
        for (int e = 0; e < 8; ++e) {
            const unsigned short hb = f2bf(bv[e]);
            bh0.s[e] = hb; bl0.s[e] = f2bf(bv[e] - bf2f(hb));
        }
        #pragma unroll
        for (int e = 0; e < 8; ++e) {
            const unsigned short hb = f2bf(bv[8 + e]);
            bh1.s[e] = hb; bl1.s[e] = f2bf(bv[8 + e] - bf2f(hb));
        }
        if (emit_ckp)
            *(uint4*)&ckp_dst[(k0 + scA) >> 1] = hA.v;

        __syncthreads();
        *(uint4*)&As_h[srA * 64 + swA] = hA.v;
        *(uint4*)&As_l[srA * 64 + swA] = lA.v;
        *(uint4*)&Bs_h[swB0] = bh0.v;  *(uint4*)&Bs_h[swB1] = bh1.v;
        *(uint4*)&Bs_l[swB0] = bl0.v;  *(uint4*)&Bs_l[swB1] = bl1.v;
        __syncthreads();

        if (k0 + 64 < 512) {
            pa0 = *(const float4*)&gA[k0 + 64];
            pa1 = *(const float4*)&gA[k0 + 68];
            #pragma unroll
            for (int kk = 0; kk < 16; ++kk)
                bv[kk] = gB[(size_t)(k0 + 64 + kk) * 512];
        }

        #pragma unroll
        for (int ks = 0; ks < 2; ++ks) {
            const int cchunk = ks * 4 + quad;
            const int m = wm + fr;
            const bf16x8 afh = *(const bf16x8*)&As_h[m * 64 + ((cchunk ^ (m & 7)) * 8)];
            const bf16x8 afl = *(const bf16x8*)&As_l[m * 64 + ((cchunk ^ (m & 7)) * 8)];
            bf16x8 bfh[2], bfl[2];
            #pragma unroll
            for (int nt = 0; nt < 2; ++nt) {
                const int n = wn + nt * 16 + fr;
                bfh[nt] = *(const bf16x8*)&Bs_h[n * 64 + ((cchunk ^ (n & 7)) * 8)];
                bfl[nt] = *(const bf16x8*)&Bs_l[n * 64 + ((cchunk ^ (n & 7)) * 8)];
            }
            #pragma unroll
            for (int nt = 0; nt < 2; ++nt) {
                acc[nt] = __builtin_amdgcn_mfma_f32_16x16x32_bf16(afh, bfh[nt], acc[nt], 0, 0, 0);
                acc[nt] = __builtin_amdgcn_mfma_f32_16x16x32_bf16(afh, bfl[nt], acc[nt], 0, 0, 0);
                acc[nt] = __builtin_amdgcn_mfma_f32_16x16x32_bf16(afl, bfh[nt], acc[nt], 0, 0, 0);
            }
        }
    }

    #pragma unroll
    for (int nt = 0; nt < 2; ++nt) {
        const int colg = col0 + wn + nt * 16 + fr;
        const float b1v = b1[colg];
        #pragma unroll
        for (int i = 0; i < 4; ++i) {
            const int rowg = row0 + wm + quad * 4 + i;
            const float v = acc[nt][i];
            if (isK) {
                const float e = fexp2((v + b1v) * C2L2E);
                const float ep = __shfl_xor(e, 1, 64);
                unsigned pk = ((fr & 1) == 0) ? packbf(e, ep) : packbf(ep, e);
                const unsigned pk2 = __shfl_xor(pk, 2, 64);
                if ((fr & 3) == 0) {
                    const int kidx = rowg >> 3;
                    const int bb   = rowg & 7;
                    const int hq   = colg >> 2;
                    ektq[((size_t)bb * 128 + hq) * 256 + kidx] = make_uint2(pk, pk2);
                }
            } else {
                eq[(size_t)(rowg - 2048) * 512 + colg] = fexp2(v * C2L2E);
            }
        }
    }
}

// ---------------------------------------------------------------------------
// Kernel 2: fused score + softmax + antvec — FOUR q per block, 1024 threads.
// Grid (32,8) = 256 blocks = 1/CU x 16 waves (same waves/CU as R14) but each
// ektq/ckp load serves 4 q (R16 lesson: load amortization >> occupancy).
// Score: thread = (k = t&255, quarter = t>>8 owns 32 hq); 4 racc chains.
// Antvec: 16 waves, wave -> 32 h, lane = (kq = lane>>3, hq = lane&7);
// 3-step shfl combine over 8 k-residues; lanes 0-7 store 4 q rows.
// ---------------------------------------------------------------------------
__global__ __launch_bounds__(1024, 4) void scoreav_kernel(
    const uint2* __restrict__ ektq, const float* __restrict__ eq,
    const float* __restrict__ W2, const float* __restrict__ b2,
    const int* __restrict__ mask, const unsigned int* __restrict__ ckp,
    float* __restrict__ prob_out, float* __restrict__ out_ant)
{
    const int t    = threadIdx.x;
    const int lane = t & 63;
    const int wave = __builtin_amdgcn_readfirstlane(t >> 6);
    const int kk   = t & 255;
    const int qtr  = t >> 8;             // 0..3: owns hq in [qtr*32, qtr*32+32)
    const int q0   = blockIdx.x * 4;
    const int b    = blockIdx.y;

    __shared__ float eqs[4][512];        // 8 KB
    __shared__ float w2s[512];           // 2 KB
    __shared__ float rp[4][4][256];      // [qi][qtr][k], 16 KB
    __shared__ float ps[4][256];         // 4 KB

    // stage eq rows (2048 floats) + w2s (512)
    {
        float* eqsf = &eqs[0][0];
        #pragma unroll
        for (int i = 0; i < 2; ++i) {
            const int idx = t + i * 1024;
            const int qi = idx >> 9, h = idx & 511;
            eqsf[idx] = eq[((size_t)(q0 + qi) * 8 + b) * 512 + h];
        }
        if (t < 512) w2s[t] = W2[t];
    }

    const float4 wA = *(const float4*)&W2[lane * 4];
    const float4 wB = *(const float4*)&W2[256 + lane * 4];
    float s2 = wA.x + wA.y + wA.z + wA.w + wB.x + wB.y + wB.z + wB.w;
    #pragma unroll
    for (int m = 32; m; m >>= 1) s2 += __shfl_xor(s2, m, 64);
    const float base = s2 + b2[0];
    __syncthreads();

    // ---- score: 32 hq per thread, double-buffered 8-load batches, 4 q ----
    const uint2* __restrict__ ekb = ektq + (size_t)b * 128 * 256 + kk;
    float racc[4] = {0.f, 0.f, 0.f, 0.f};

    uint2 L[2][8];
    #pragma unroll
    for (int j = 0; j < 8; ++j)
        L[0][j] = ekb[(size_t)(qtr * 32 + j) * 256];

    for (int g = 0; g < 4; ++g) {
        const int cur = g & 1;
        if (g < 3) {
            #pragma unroll
            for (int j = 0; j < 8; ++j)
                L[cur ^ 1][j] = ekb[(size_t)(qtr * 32 + (g + 1) * 8 + j) * 256];
        }
        #pragma unroll
        for (int j = 0; j < 8; ++j) {
            const int h = (qtr * 32 + g * 8 + j) * 4;
            const float ek0 = lo16(L[cur][j].x);
            const float ek1 = hi16(L[cur][j].x);
            const float ek2 = lo16(L[cur][j].y);
            const float ek3 = hi16(L[cur][j].y);
            const float4 w = *(const float4*)&w2s[h];
            #pragma unroll
            for (int qi = 0; qi < 4; ++qi) {
                const float4 e0 = *(const float4*)&eqs[qi][h];
                const float a0 = fmaf(ek0, e0.x, 1.0f);
                const float a1 = fmaf(ek1, e0.y, 1.0f);
                const float a2 = fmaf(ek2, e0.z, 1.0f);
                const float a3 = fmaf(ek3, e0.w, 1.0f);
                const float d01 = a0 * a1, d23 = a2 * a3;
                const float n01 = fmaf(w.x, a1, w.y * a0);
                const float n23 = fmaf(w.z, a3, w.w * a2);
                const float N = fmaf(n01, d23, n23 * d01);
                racc[qi] = fmaf(N, frcp(d01 * d23), racc[qi]);
            }
        }
    }
    #pragma unroll
    for (int qi = 0; qi < 4; ++qi) rp[qi][qtr][kk] = racc[qi];
    __syncthreads();

    // ---- combine quarters + mask -> ps ----
    if (t < 256) {
        const int msk = mask[t * 8 + b];
        #pragma unroll
        for (int qi = 0; qi < 4; ++qi) {
            float s0 = base - 2.0f * ((rp[qi][0][t] + rp[qi][1][t]) +
                                      (rp[qi][2][t] + rp[qi][3][t]));
            if (msk) s0 = -INFINITY;
            ps[qi][t] = s0;
        }
    }
    __syncthreads();

    // ---- softmax: waves 0..3 (wave = qi) ----
    if (wave < 4) {
        const int qi = wave;
        float4 sv = *(const float4*)&ps[qi][lane * 4];
        float m = fmaxf(fmaxf(sv.x, sv.y), fmaxf(sv.z, sv.w));
        #pragma unroll
        for (int d = 32; d; d >>= 1) m = fmaxf(m, __shfl_xor(m, d, 64));
        float4 pv;
        pv.x = fexp2((sv.x - m) * L2E);
        pv.y = fexp2((sv.y - m) * L2E);
        pv.z = fexp2((sv.z - m) * L2E);
        pv.w = fexp2((sv.w - m) * L2E);
        float sum = pv.x + pv.y + pv.z + pv.w;
        #pragma unroll
        for (int d = 32; d; d >>= 1) sum += __shfl_xor(sum, d, 64);
        const float inv = frcp(sum);
        pv.x *= inv; pv.y *= inv; pv.z *= inv; pv.w *= inv;
        *(float4*)&ps[qi][lane * 4] = pv;
        const int qb_idx = (q0 + qi) * 8 + b;
        const int kbase = lane * 4;
        prob_out[(size_t)(kbase + 0) * 1024 + qb_idx] = pv.x;
        prob_out[(size_t)(kbase + 1) * 1024 + qb_idx] = pv.y;
        prob_out[(size_t)(kbase + 2) * 1024 + qb_idx] = pv.z;
        prob_out[(size_t)(kbase + 3) * 1024 + qb_idx] = pv.w;
    }
    __syncthreads();

    // ---- antvec: 16 waves, wave -> 32 h; lane = (kq = lane>>3, hq = lane&7) ----
    {
        const int kq = lane >> 3;          // 0..7 (k residue mod 8)
        const int hq = lane & 7;           // 0..7 (h-quad within wave's 32 h)
        const int pbase = wave * 16 + hq * 2;   // bf16-pair index
        const unsigned int* __restrict__ ckb = ckp + (size_t)b * 256 * 256;
        float4 a[4] = {};
        #pragma unroll 8
        for (int ki = 0; ki < 32; ++ki) {
            const int k = ki * 8 + kq;
            const uint2 U = *(const uint2*)&ckb[(size_t)k * 256 + pbase];
            const float c0 = lo16(U.x), c1 = hi16(U.x);
            const float c2 = lo16(U.y), c3 = hi16(U.y);
            #pragma unroll
            for (int qi = 0; qi < 4; ++qi) {
                const float p = ps[qi][k];
                a[qi].x = fmaf(p, c0, a[qi].x);
                a[qi].y = fmaf(p, c1, a[qi].y);
                a[qi].z = fmaf(p, c2, a[qi].z);
                a[qi].w = fmaf(p, c3, a[qi].w);
            }
        }
        #pragma unroll
        for (int d = 8; d <= 32; d <<= 1) {
            #pragma unroll
            for (int qi = 0; qi < 4; ++qi) {
                a[qi].x += __shfl_xor(a[qi].x, d, 64);
                a[qi].y += __shfl_xor(a[qi].y, d, 64);
                a[qi].z += __shfl_xor(a[qi].z, d, 64);
                a[qi].w += __shfl_xor(a[qi].w, d, 64);
            }
        }
        if (lane < 8) {
            const int h0 = wave * 32 + hq * 4;
            #pragma unroll
            for (int qi = 0; qi < 4; ++qi)
                *(float4*)&out_ant[((size_t)(q0 + qi) * 8 + b) * 512 + h0] = a[qi];
        }
    }
}

// ---------------------------------------------------------------------------
extern "C" void kernel_launch(void* const* d_in, const int* in_sizes, int n_in,
                              void* d_out, int out_size, void* d_ws, size_t ws_size,
                              hipStream_t stream)
{
    const float* qry  = (const float*)d_in[0];
    const float* ckey = (const float*)d_in[1];
    const int*   mask = (const int*)d_in[2];
    const float* W1   = (const float*)d_in[3];
    const float* b1   = (const float*)d_in[4];
    const float* W2   = (const float*)d_in[5];
    const float* b2   = (const float*)d_in[6];

    float* out_ant  = (float*)d_out;
    float* out_prob = (float*)d_out + T_Q * BB * NHID;

    float* ws = (float*)d_ws;
    uint2* ws_ektq = (uint2*)ws;                              // [8][128][256] uint2, 2MB
    float* ws_eq  = ws + 524288;                              // [1024][512] f32, 2MB
    unsigned int* ws_ckp = (unsigned int*)(ws + 1048576);     // [8][256][256] u32, 2MB

    proj_kernel<<<dim3(96, 8), 256, 0, stream>>>(qry, ckey, W1, b1,
                                                 ws_ektq, ws_eq, ws_ckp);
    scoreav_kernel<<<dim3(32, 8), 1024, 0, stream>>>(ws_ektq, ws_eq, W2, b2, mask, ws_ckp,
                                                     out_prob, out_ant);
}

// Round 18
// 110.767 us; speedup vs baseline: 1.0970x; 1.0149x over previous
//
#include <hip/hip_runtime.h>
#include <math.h>

#define NHID 512
#define T_K  256
#define T_Q  128
#define BB   8

// tanh(x) = 1 - 2/(exp2(C*x)+1), C = 2*log2(e)
constexpr float C2L2E = 2.8853900817779268f;
constexpr float L2E   = 1.4426950408889634f;

__device__ __forceinline__ float fexp2(float x) { return __builtin_amdgcn_exp2f(x); }
__device__ __forceinline__ float frcp(float x)  { return __builtin_amdgcn_rcpf(x); }

typedef __attribute__((ext_vector_type(8))) short bf16x8;
typedef __attribute__((ext_vector_type(4))) float f32x4;

__device__ __forceinline__ unsigned short f2bf(float x) {
    unsigned u = __builtin_bit_cast(unsigned, x);
    unsigned r = (u + 0x7FFFu + ((u >> 16) & 1u)) >> 16;
    return (unsigned short)r;
}
__device__ __forceinline__ float bf2f(unsigned short h) {
    unsigned u = ((unsigned)h) << 16;
    return __builtin_bit_cast(float, u);
}
__device__ __forceinline__ unsigned packbf(float a, float b) {
    return (unsigned)f2bf(a) | ((unsigned)f2bf(b) << 16);
}
__device__ __forceinline__ float lo16(unsigned u) {
    return __builtin_bit_cast(float, u << 16);
}
__device__ __forceinline__ float hi16(unsigned u) {
    return __builtin_bit_cast(float, u & 0xFFFF0000u);
}

// ---------------------------------------------------------------------------
// Kernel 1: proj GEMM, in-kernel W1 transpose/split, free ckp emission.
// Epilogue K-side now packs an h-OCTET (8 bf16) per store: pk/pk2 (R15) plus
// shfl_xor(...,4) partners -> fr%8==0 lanes store uint4 to ekto[b][ho][k].
// ---------------------------------------------------------------------------
__global__ __launch_bounds__(256) void proj_kernel(
    const float* __restrict__ qry, const float* __restrict__ ckey,
    const float* __restrict__ W1, const float* __restrict__ b1,
    uint4* __restrict__ ekto, float* __restrict__ eq,
    unsigned int* __restrict__ ckp)
{
    const int row0 = blockIdx.x * 32;
    const int col0 = blockIdx.y * 64;
    const bool isK = row0 < 2048;
    const int bhalf = isK ? 0 : 512;

    __shared__ __align__(16) unsigned short As_h[32 * 64];
    __shared__ __align__(16) unsigned short As_l[32 * 64];
    __shared__ __align__(16) unsigned short Bs_h[64 * 64];
    __shared__ __align__(16) unsigned short Bs_l[64 * 64];

    const int t    = threadIdx.x;
    const int wave = t >> 6;
    const int lane = t & 63;
    const int wm = (wave & 1) * 16;
    const int wn = (wave >> 1) * 32;

    f32x4 acc[2] = {};

    const int srA = t >> 3;
    const int scA = (t & 7) * 8;
    const float* gA = (isK ? ckey + (size_t)(row0 + srA) * 512
                           : qry  + (size_t)(row0 - 2048 + srA) * 512) + scA;
    const int swA = ((scA >> 3) ^ (srA & 7)) * 8;
    const bool emit_ckp = isK && (col0 == 0);
    const int rowA = row0 + srA;
    unsigned int* ckp_dst = emit_ckp
        ? ckp + ((size_t)(rowA & 7) * 256 + (rowA >> 3)) * 256
        : nullptr;

    const int nB = t & 63;
    const int kgB = wave * 16;
    const float* gB = W1 + (size_t)(bhalf + kgB) * 512 + col0 + nB;
    const int caB = wave * 2;
    const int swB0 = nB * 64 + (((caB + 0) ^ (nB & 7)) * 8);
    const int swB1 = nB * 64 + (((caB + 1) ^ (nB & 7)) * 8);

    const int quad = lane >> 4, fr = lane & 15;

    float4 pa0 = *(const float4*)&gA[0];
    float4 pa1 = *(const float4*)&gA[4];
    float bv[16];
    #pragma unroll
    for (int kk = 0; kk < 16; ++kk)
        bv[kk] = gB[(size_t)kk * 512];

    for (int k0 = 0; k0 < 512; k0 += 64) {
        float fa[8];
        *(float4*)&fa[0] = pa0; *(float4*)&fa[4] = pa1;
        union { uint4 v; unsigned short s[8]; } hA, lA, bh0, bh1, bl0, bl1;
        #pragma unroll
        for (int e = 0; e < 8; ++e) {
            const unsigned short hb = f2bf(fa[e]);
            hA.s[e] = hb; lA.s[e] = f2bf(fa[e] - bf2f(hb));
        }
        #pragma unroll
        for (int e = 0; e < 8; ++e) {
            const unsigned short hb = f2bf(bv[e]);
            bh0.s[e] = hb; bl0.s[e] = f2bf(bv[e] - bf2f(hb));
        }
        #pragma unroll
        for (int e = 0; e < 8; ++e) {
            const unsigned short hb = f2bf(bv[8 + e]);
            bh1.s[e] = hb; bl1.s[e] = f2bf(bv[8 + e] - bf2f(hb));
        }
        if (emit_ckp)
            *(uint4*)&ckp_dst[(k0 + scA) >> 1] = hA.v;

        __syncthreads();
        *(uint4*)&As_h[srA * 64 + swA] = hA.v;
        *(uint4*)&As_l[srA * 64 + swA] = lA.v;
        *(uint4*)&Bs_h[swB0] = bh0.v;  *(uint4*)&Bs_h[swB1] = bh1.v;
        *(uint4*)&Bs_l[swB0] = bl0.v;  *(uint4*)&Bs_l[swB1] = bl1.v;
        __syncthreads();

        if (k0 + 64 < 512) {
            pa0 = *(const float4*)&gA[k0 + 64];
            pa1 = *(const float4*)&gA[k0 + 68];
            #pragma unroll
            for (int kk = 0; kk < 16; ++kk)
                bv[kk] = gB[(size_t)(k0 + 64 + kk) * 512];
        }

        #pragma unroll
        for (int ks = 0; ks < 2; ++ks) {
            const int cchunk = ks * 4 + quad;
            const int m = wm + fr;
            const bf16x8 afh = *(const bf16x8*)&As_h[m * 64 + ((cchunk ^ (m & 7)) * 8)];
            const bf16x8 afl = *(const bf16x8*)&As_l[m * 64 + ((cchunk ^ (m & 7)) * 8)];
            bf16x8 bfh[2], bfl[2];
            #pragma unroll
            for (int nt = 0; nt < 2; ++nt) {
                const int n = wn + nt * 16 + fr;
                bfh[nt] = *(const bf16x8*)&Bs_h[n * 64 + ((cchunk ^ (n & 7)) * 8)];
                bfl[nt] = *(const bf16x8*)&Bs_l[n * 64 + ((cchunk ^ (n & 7)) * 8)];
            }
            #pragma unroll
            for (int nt = 0; nt < 2; ++nt) {
                acc[nt] = __builtin_amdgcn_mfma_f32_16x16x32_bf16(afh, bfh[nt], acc[nt], 0, 0, 0);
                acc[nt] = __builtin_amdgcn_mfma_f32_16x16x32_bf16(afh, bfl[nt], acc[nt], 0, 0, 0);
                acc[nt] = __builtin_amdgcn_mfma_f32_16x16x32_bf16(afl, bfh[nt], acc[nt], 0, 0, 0);
            }
        }
    }

    #pragma unroll
    for (int nt = 0; nt < 2; ++nt) {
        const int colg = col0 + wn + nt * 16 + fr;
        const float b1v = b1[colg];
        #pragma unroll
        for (int i = 0; i < 4; ++i) {
            const int rowg = row0 + wm + quad * 4 + i;
            const float v = acc[nt][i];
            if (isK) {
                const float e = fexp2((v + b1v) * C2L2E);
                const float ep = __shfl_xor(e, 1, 64);
                unsigned pk = ((fr & 1) == 0) ? packbf(e, ep) : packbf(ep, e);
                unsigned pk2 = __shfl_xor(pk, 2, 64);
                if (fr & 2) { unsigned tmp = pk; pk = pk2; pk2 = tmp; }
                // now every lane: pk = (h_base, h_base+1), pk2 = (h_base+2, h_base+3)
                const unsigned px  = __shfl_xor(pk, 4, 64);
                const unsigned px2 = __shfl_xor(pk2, 4, 64);
                if ((fr & 7) == 0) {
                    const int kidx = rowg >> 3;
                    const int bb   = rowg & 7;
                    const int ho   = colg >> 3;
                    ekto[((size_t)bb * 64 + ho) * 256 + kidx] =
                        make_uint4(pk, pk2, px, px2);
                }
            } else {
                eq[(size_t)(rowg - 2048) * 512 + colg] = fexp2(v * C2L2E);
            }
        }
    }
}

// ---------------------------------------------------------------------------
// Kernel 2: fused score + softmax + antvec. R14 config (2 q, 512 thr,
// grid (64,8) = 512 blocks = 2/CU) with OCTET loads:
// score: 32 dwordx4 loads/thread (was 64 dwordx2), double-buffered 4-load
// batches, 4 acc chains. antvec: uint4 ckp reads, 8 h/lane, 3-step shfl.
// ---------------------------------------------------------------------------
__global__ __launch_bounds__(512) void scoreav_kernel(
    const uint4* __restrict__ ekto, const float* __restrict__ eq,
    const float* __restrict__ W2, const float* __restrict__ b2,
    const int* __restrict__ mask, const unsigned int* __restrict__ ckp,
    float* __restrict__ prob_out, float* __restrict__ out_ant)
{
    const int t    = threadIdx.x;
    const int lane = t & 63;
    const int wave = __builtin_amdgcn_readfirstlane(t >> 6);
    const int kk   = t & 255;
    const int half = t >> 8;
    const int q0   = blockIdx.x * 2;
    const int b    = blockIdx.y;

    __shared__ float eq0s[512], eq1s[512], w2s[512];   // 6 KB
    __shared__ float rp[2][512];                       // 4 KB
    __shared__ float ps[2][256];                       // 2 KB

    eq0s[t] = eq[((size_t)q0 * 8 + b) * 512 + t];
    eq1s[t] = eq[((size_t)(q0 + 1) * 8 + b) * 512 + t];
    w2s[t]  = W2[t];

    const float4 wA = *(const float4*)&W2[lane * 4];
    const float4 wB = *(const float4*)&W2[256 + lane * 4];
    float s2 = wA.x + wA.y + wA.z + wA.w + wB.x + wB.y + wB.z + wB.w;
    #pragma unroll
    for (int m = 32; m; m >>= 1) s2 += __shfl_xor(s2, m, 64);
    const float base = s2 + b2[0];
    __syncthreads();

    // ---- score: thread owns (k=kk, h-octets half*32..half*32+31) ----
    const uint4* __restrict__ ekb = ekto + (size_t)b * 64 * 256 + kk;
    float r0a = 0.f, r0b = 0.f, r1a = 0.f, r1b = 0.f;

    uint4 L[2][4];
    #pragma unroll
    for (int j = 0; j < 4; ++j)
        L[0][j] = ekb[(size_t)(half * 32 + j) * 256];

    for (int g = 0; g < 8; ++g) {
        const int cur = g & 1;
        if (g < 7) {
            #pragma unroll
            for (int j = 0; j < 4; ++j)
                L[cur ^ 1][j] = ekb[(size_t)(half * 32 + (g + 1) * 4 + j) * 256];
        }
        #pragma unroll
        for (int j = 0; j < 4; ++j) {
            const int h = (half * 32 + g * 4 + j) * 8;
            const uint4 U = L[cur][j];
            const float ek0 = lo16(U.x), ek1 = hi16(U.x);
            const float ek2 = lo16(U.y), ek3 = hi16(U.y);
            const float ek4 = lo16(U.z), ek5 = hi16(U.z);
            const float ek6 = lo16(U.w), ek7 = hi16(U.w);
            const float4 wL = *(const float4*)&w2s[h];
            const float4 wH = *(const float4*)&w2s[h + 4];
            {   // q0
                const float4 eL = *(const float4*)&eq0s[h];
                const float4 eH = *(const float4*)&eq0s[h + 4];
                {
                    const float a0 = fmaf(ek0, eL.x, 1.0f);
                    const float a1 = fmaf(ek1, eL.y, 1.0f);
                    const float a2 = fmaf(ek2, eL.z, 1.0f);
                    const float a3 = fmaf(ek3, eL.w, 1.0f);
                    const float d01 = a0 * a1, d23 = a2 * a3;
                    const float n01 = fmaf(wL.x, a1, wL.y * a0);
                    const float n23 = fmaf(wL.z, a3, wL.w * a2);
                    const float N = fmaf(n01, d23, n23 * d01);
                    r0a = fmaf(N, frcp(d01 * d23), r0a);
                }
                {
                    const float a0 = fmaf(ek4, eH.x, 1.0f);
                    const float a1 = fmaf(ek5, eH.y, 1.0f);
                    const float a2 = fmaf(ek6, eH.z, 1.0f);
                    const float a3 = fmaf(ek7, eH.w, 1.0f);
                    const float d01 = a0 * a1, d23 = a2 * a3;
                    const float n01 = fmaf(wH.x, a1, wH.y * a0);
                    const float n23 = fmaf(wH.z, a3, wH.w * a2);
                    const float N = fmaf(n01, d23, n23 * d01);
                    r0b = fmaf(N, frcp(d01 * d23), r0b);
                }
            }
            {   // q1
                const float4 eL = *(const float4*)&eq1s[h];
                const float4 eH = *(const float4*)&eq1s[h + 4];
                {
                    const float a0 = fmaf(ek0, eL.x, 1.0f);
                    const float a1 = fmaf(ek1, eL.y, 1.0f);
                    const float a2 = fmaf(ek2, eL.z, 1.0f);
                    const float a3 = fmaf(ek3, eL.w, 1.0f);
                    const float d01 = a0 * a1, d23 = a2 * a3;
                    const float n01 = fmaf(wL.x, a1, wL.y * a0);
                    const float n23 = fmaf(wL.z, a3, wL.w * a2);
                    const float N = fmaf(n01, d23, n23 * d01);
                    r1a = fmaf(N, frcp(d01 * d23), r1a);
                }
                {
                    const float a0 = fmaf(ek4, eH.x, 1.0f);
                    const float a1 = fmaf(ek5, eH.y, 1.0f);
                    const float a2 = fmaf(ek6, eH.z, 1.0f);
                    const float a3 = fmaf(ek7, eH.w, 1.0f);
                    const float d01 = a0 * a1, d23 = a2 * a3;
                    const float n01 = fmaf(wH.x, a1, wH.y * a0);
                    const float n23 = fmaf(wH.z, a3, wH.w * a2);
                    const float N = fmaf(n01, d23, n23 * d01);
                    r1b = fmaf(N, frcp(d01 * d23), r1b);
                }
            }
        }
    }
    rp[0][t] = r0a + r0b;
    rp[1][t] = r1a + r1b;
    __syncthreads();

    if (t < 256) {
        const int msk = mask[t * 8 + b];
        float s0 = base - 2.0f * (rp[0][t] + rp[0][t + 256]);
        float s1 = base - 2.0f * (rp[1][t] + rp[1][t + 256]);
        if (msk) { s0 = -INFINITY; s1 = -INFINITY; }
        ps[0][t] = s0;
        ps[1][t] = s1;
    }
    __syncthreads();

    // ---- softmax: waves 0,1 ----
    if (wave < 2) {
        float4 sv = *(const float4*)&ps[wave][lane * 4];
        float m = fmaxf(fmaxf(sv.x, sv.y), fmaxf(sv.z, sv.w));
        #pragma unroll
        for (int d = 32; d; d >>= 1) m = fmaxf(m, __shfl_xor(m, d, 64));
        float4 pv;
        pv.x = fexp2((sv.x - m) * L2E);
        pv.y = fexp2((sv.y - m) * L2E);
        pv.z = fexp2((sv.z - m) * L2E);
        pv.w = fexp2((sv.w - m) * L2E);
        float sum = pv.x + pv.y + pv.z + pv.w;
        #pragma unroll
        for (int d = 32; d; d >>= 1) sum += __shfl_xor(sum, d, 64);
        const float inv = frcp(sum);
        pv.x *= inv; pv.y *= inv; pv.z *= inv; pv.w *= inv;
        *(float4*)&ps[wave][lane * 4] = pv;
        const int qb_idx = (q0 + wave) * 8 + b;
        const int kbase = lane * 4;
        prob_out[(size_t)(kbase + 0) * 1024 + qb_idx] = pv.x;
        prob_out[(size_t)(kbase + 1) * 1024 + qb_idx] = pv.y;
        prob_out[(size_t)(kbase + 2) * 1024 + qb_idx] = pv.z;
        prob_out[(size_t)(kbase + 3) * 1024 + qb_idx] = pv.w;
    }
    __syncthreads();

    // ---- antvec: wave -> 64 h; lane = (kq = lane>>3, hq = lane&7, 8 h) ----
    {
        const int kq = lane >> 3;          // 0..7 (k residue mod 8)
        const int hq = lane & 7;           // 0..7 (h-octet within wave's 64 h)
        const int pbase = wave * 32 + hq * 4;   // bf16-pair index
        const unsigned int* __restrict__ ckb = ckp + (size_t)b * 256 * 256;
        float4 a0q0 = {}, a1q0 = {}, a0q1 = {}, a1q1 = {};
        #pragma unroll 8
        for (int ki = 0; ki < 32; ++ki) {
            const int k = ki * 8 + kq;
            const uint4 U = *(const uint4*)&ckb[(size_t)k * 256 + pbase];
            const float c0 = lo16(U.x), c1 = hi16(U.x);
            const float c2 = lo16(U.y), c3 = hi16(U.y);
            const float c4 = lo16(U.z), c5 = hi16(U.z);
            const float c6 = lo16(U.w), c7 = hi16(U.w);
            const float p0 = ps[0][k];
            const float p1 = ps[1][k];
            a0q0.x = fmaf(p0, c0, a0q0.x); a0q0.y = fmaf(p0, c1, a0q0.y);
            a0q0.z = fmaf(p0, c2, a0q0.z); a0q0.w = fmaf(p0, c3, a0q0.w);
            a1q0.x = fmaf(p0, c4, a1q0.x); a1q0.y = fmaf(p0, c5, a1q0.y);
            a1q0.z = fmaf(p0, c6, a1q0.z); a1q0.w = fmaf(p0, c7, a1q0.w);
            a0q1.x = fmaf(p1, c0, a0q1.x); a0q1.y = fmaf(p1, c1, a0q1.y);
            a0q1.z = fmaf(p1, c2, a0q1.z); a0q1.w = fmaf(p1, c3, a0q1.w);
            a1q1.x = fmaf(p1, c4, a1q1.x); a1q1.y = fmaf(p1, c5, a1q1.y);
            a1q1.z = fmaf(p1, c6, a1q1.z); a1q1.w = fmaf(p1, c7, a1q1.w);
        }
        #pragma unroll
        for (int d = 8; d <= 32; d <<= 1) {
            a0q0.x += __shfl_xor(a0q0.x, d, 64); a0q0.y += __shfl_xor(a0q0.y, d, 64);
            a0q0.z += __shfl_xor(a0q0.z, d, 64); a0q0.w += __shfl_xor(a0q0.w, d, 64);
            a1q0.x += __shfl_xor(a1q0.x, d, 64); a1q0.y += __shfl_xor(a1q0.y, d, 64);
            a1q0.z += __shfl_xor(a1q0.z, d, 64); a1q0.w += __shfl_xor(a1q0.w, d, 64);
            a0q1.x += __shfl_xor(a0q1.x, d, 64); a0q1.y += __shfl_xor(a0q1.y, d, 64);
            a0q1.z += __shfl_xor(a0q1.z, d, 64); a0q1.w += __shfl_xor(a0q1.w, d, 64);
            a1q1.x += __shfl_xor(a1q1.x, d, 64); a1q1.y += __shfl_xor(a1q1.y, d, 64);
            a1q1.z += __shfl_xor(a1q1.z, d, 64); a1q1.w += __shfl_xor(a1q1.w, d, 64);
        }
        if (lane < 8) {
            const int h0 = wave * 64 + hq * 8;
            float* o0 = &out_ant[((size_t)q0 * 8 + b) * 512 + h0];
            float* o1 = &out_ant[((size_t)(q0 + 1) * 8 + b) * 512 + h0];
            *(float4*)&o0[0] = a0q0;  *(float4*)&o0[4] = a1q0;
            *(float4*)&o1[0] = a0q1;  *(float4*)&o1[4] = a1q1;
        }
    }
}

// ---------------------------------------------------------------------------
extern "C" void kernel_launch(void* const* d_in, const int* in_sizes, int n_in,
                              void* d_out, int out_size, void* d_ws, size_t ws_size,
                              hipStream_t stream)
{
    const float* qry  = (const float*)d_in[0];
    const float* ckey = (const float*)d_in[1];
    const int*   mask = (const int*)d_in[2];
    const float* W1   = (const float*)d_in[3];
    const float* b1   = (const float*)d_in[4];
    const float* W2   = (const float*)d_in[5];
    const float* b2   = (const float*)d_in[6];

    float* out_ant  = (float*)d_out;
    float* out_prob = (float*)d_out + T_Q * BB * NHID;

    float* ws = (float*)d_ws;
    uint4* ws_ekto = (uint4*)ws;                              // [8][64][256] uint4, 2MB
    float* ws_eq  = ws + 524288;                              // [1024][512] f32, 2MB
    unsigned int* ws_ckp = (unsigned int*)(ws + 1048576);     // [8][256][256] u32, 2MB

    proj_kernel<<<dim3(96, 8), 256, 0, stream>>>(qry, ckey, W1, b1,
                                                 ws_ekto, ws_eq, ws_ckp);
    scoreav_kernel<<<dim3(64, 8), 512, 0, stream>>>(ws_ekto, ws_eq, W2, b2, mask, ws_ckp,
                                                    out_prob, out_ant);
}